// Round 8
// baseline (732.812 us; speedup 1.0000x reference)
//
#include <hip/hip_runtime.h>
#include <math.h>
#include <stdint.h>

#define N_ATOMS 60000
#define M_NBR   12
#define NBF     41
#define B_CRYS  2048
#define EPSBN   1e-5f
#define GA      8                 // atoms per fused block
#define GRID_F  (N_ATOMS / GA)    // 7500
#define WIMG_L  24576             // shorts per layer: [edge][self][nbr] x 8192
#define SSTR    56                // LDS row stride (shorts), 112B -> 16B aligned

typedef __attribute__((ext_vector_type(8))) short bf8;
typedef __attribute__((ext_vector_type(4))) float f32x4;
#define MFMA_B16(a, b, c) __builtin_amdgcn_mfma_f32_16x16x32_bf16(a, b, c, 0, 0, 0)

__device__ __forceinline__ short f2bf(float f) {
  uint32_t u = __builtin_bit_cast(uint32_t, f);
  u += 0x7FFFu + ((u >> 16) & 1u);
  return (short)(u >> 16);
}
__device__ __forceinline__ float sp(float x) {
  return (x > 15.f) ? x : __logf(1.f + __expf(x));
}
__device__ __forceinline__ float sig(float x) {
  return 1.f / (1.f + __expf(-x));
}

// ---------------------------------------------------------------------------
// Weight-image prep: bn1-folded bf16 B-fragments, MFMA lane order.
// per layer: [which 0=edge,1=self,2=nbr][frag=ct*2+ks][lane][8]
// image col j -> orig col (j>>1) + 64*(j&1)   (flt/core pairing)
// Edge image row k=41 holds bn1-folded bias; fused kernel sets A[k=41]=1.0.
// ---------------------------------------------------------------------------
__global__ __launch_bounds__(256) void k_wprep(
    const float* __restrict__ conv_W, const float* __restrict__ conv_b,
    const float* __restrict__ bn1_g, const float* __restrict__ bn1_b,
    unsigned short* __restrict__ Wimg) {
  const int gid = blockIdx.x * 256 + threadIdx.x;
  if (gid >= 3 * WIMG_L) return;
  const int layer = gid / WIMG_L, rem = gid % WIMG_L;
  const int which = rem / 8192, r2 = rem % 8192;
  const int frag = r2 >> 9, lane = (r2 >> 3) & 63, j = r2 & 7;
  const int ct = frag >> 1, ks = frag & 1;
  const int quad = lane >> 4, l15 = lane & 15;
  const int jc = ct * 16 + l15;
  const int oc = (jc & 1) ? (jc >> 1) + 64 : (jc >> 1);
  const float s = bn1_g[layer * 128 + oc] * rsqrtf(1.f + EPSBN);
  const int k = ks * 32 + quad * 8 + j;
  const float* Wc = conv_W + (size_t)layer * 169 * 128;
  float v = 0.f;
  if (which == 0) {
    if (k < NBF) v = Wc[(128 + k) * 128 + oc] * s;
    else if (k == NBF) v = conv_b[layer * 128 + oc] * s + bn1_b[layer * 128 + oc];
  } else if (which == 1) {
    v = Wc[k * 128 + oc] * s;
  } else {
    v = Wc[(64 + k) * 128 + oc] * s;
  }
  Wimg[gid] = (unsigned short)f2bf(v);
}

// ---------------------------------------------------------------------------
// X = atom_fea @ W_embed + b_embed (MFMA); X fp32 + packed-dword bf16 shadow.
// ---------------------------------------------------------------------------
__global__ __launch_bounds__(256) void k_embed2(
    const float* __restrict__ A, const float* __restrict__ W,
    const float* __restrict__ bias, float* __restrict__ X,
    unsigned int* __restrict__ XbU) {
  const int lane = threadIdx.x & 63, wv = threadIdx.x >> 6;
  const int quad = lane >> 4, l15 = lane & 15;
  const int gw = blockIdx.x * 4 + wv, nw = gridDim.x * 4;
  bf8 Bf[3][4];
  float bs[4];
#pragma unroll
  for (int ct = 0; ct < 4; ++ct) {
    const int col = ct * 16 + l15;
    bs[ct] = bias[col];
#pragma unroll
    for (int ks = 0; ks < 3; ++ks) {
      bf8 b;
#pragma unroll
      for (int i = 0; i < 8; ++i) {
        const int k = ks * 32 + quad * 8 + i;
        b[i] = (k < 92) ? f2bf(W[k * 64 + col]) : (short)0;
      }
      Bf[ks][ct] = b;
    }
  }
  for (int rt = gw; rt < 3750; rt += nw) {
    const int rbase = rt * 16;
    const float* ar = A + (size_t)(rbase + l15) * 92;
    const float4 p0 = *(const float4*)(ar + quad * 8);
    const float4 p1 = *(const float4*)(ar + quad * 8 + 4);
    const float4 p2 = *(const float4*)(ar + 32 + quad * 8);
    const float4 p3 = *(const float4*)(ar + 32 + quad * 8 + 4);
    bf8 A0, A1, A2;
    A0[0] = f2bf(p0.x); A0[1] = f2bf(p0.y); A0[2] = f2bf(p0.z); A0[3] = f2bf(p0.w);
    A0[4] = f2bf(p1.x); A0[5] = f2bf(p1.y); A0[6] = f2bf(p1.z); A0[7] = f2bf(p1.w);
    A1[0] = f2bf(p2.x); A1[1] = f2bf(p2.y); A1[2] = f2bf(p2.z); A1[3] = f2bf(p2.w);
    A1[4] = f2bf(p3.x); A1[5] = f2bf(p3.y); A1[6] = f2bf(p3.z); A1[7] = f2bf(p3.w);
#pragma unroll
    for (int i = 0; i < 8; ++i) {
      const int k = 64 + quad * 8 + i;
      A2[i] = (k < 92) ? f2bf(ar[k]) : (short)0;
    }
    const f32x4 z = {0.f, 0.f, 0.f, 0.f};
    f32x4 acc[4];
#pragma unroll
    for (int ct = 0; ct < 4; ++ct) {
      acc[ct] = MFMA_B16(A0, Bf[0][ct], z);
      acc[ct] = MFMA_B16(A1, Bf[1][ct], acc[ct]);
      acc[ct] = MFMA_B16(A2, Bf[2][ct], acc[ct]);
    }
#pragma unroll
    for (int ct = 0; ct < 4; ++ct)
#pragma unroll
      for (int r = 0; r < 4; ++r) {
        const int row = rbase + quad * 4 + r;
        const float v = acc[ct][r] + bs[ct];
        X[(size_t)row * 64 + ct * 16 + l15] = v;
        const unsigned int u = (unsigned short)f2bf(v);
        const unsigned int p = __shfl_xor((int)u, 1);
        if (!(l15 & 1))
          XbU[(size_t)row * 32 + ct * 8 + (l15 >> 1)] = u | (p << 16);
      }
  }
}

// ---------------------------------------------------------------------------
// FUSED conv layer, register-resident gate. One MFMA tile = ONE atom
// (M padded 12->16; rows 12..15 = quad3, masked in the reduction).
//   gate = nbr_fea@We*s1 + bias + Xb[idx]@Wn*s1 + Xb[n]@Ws*s1  (MFMA chain)
//   prod = sig(flt)*sp(core) paired via shfl_xor(1) (even lanes rows 0,1;
//   odd rows 2,3), quad3 masked, row-sum via shfl_xor(1,16,32);
//   per ct one quad writes: X[n,c] = sp(X + sum*s2 + b2), Xb shadow packed.
// XbIn / XbOut distinct buffers (cross-block gather vs own-row write; G16).
// ---------------------------------------------------------------------------
__global__ __launch_bounds__(256, 6) void k_fused5(
    float* __restrict__ X, const unsigned short* __restrict__ XbIn,
    unsigned int* __restrict__ XbOutU, const float* __restrict__ NF,
    const int* __restrict__ IDX, const unsigned short* __restrict__ Wi,
    const float* __restrict__ g2, const float* __restrict__ b2) {
  __shared__ __align__(16) unsigned short sfea[96 * SSTR];  // 10752 B
  const int tid = threadIdx.x;
  const int lane = tid & 63, wv = tid >> 6;
  const int quad = lane >> 4, l15 = lane & 15;
  const int g = blockIdx.x;
  const float inv = rsqrtf(1.f + EPSBN);

  // ---- stage 96x41 nbr_fea as bf16 into LDS (row stride 56 shorts) ----
  const float* src = NF + (size_t)g * (96 * NBF);
  for (int e = tid; e < 96 * NBF; e += 256) {
    const int row = e / NBF, col = e - row * NBF;
    sfea[row * SSTR + col] = (unsigned short)f2bf(src[e]);
  }
  __syncthreads();

#pragma unroll 1
  for (int ti = 0; ti < 2; ++ti) {
    const int rt = wv * 2 + ti;  // tile = block-local atom
    const int n = g * GA + rt;
    // neighbor A (gather; padded lanes reuse edge 11 -> masked later)
    const int li = (l15 < 12) ? l15 : 11;
    const int jr = IDX[n * 12 + li];
    const unsigned short* xr = XbIn + (size_t)jr * 64 + quad * 8;
    const bf8 Ax0 = *(const bf8*)xr;
    const bf8 Ax1 = *(const bf8*)(xr + 32);
    // self A (row broadcast)
    const unsigned short* sr = XbIn + (size_t)n * 64 + quad * 8;
    const bf8 As0 = *(const bf8*)sr;
    const bf8 As1 = *(const bf8*)(sr + 32);
    // edge A from LDS (k=41 := 1.0 bias slot; k>41 zero)
    const unsigned short* ep = sfea + (rt * 12 + li) * SSTR;
    const bf8 Ae0 = *(const bf8*)(ep + quad * 8);
    bf8 Ae1 = {0, 0, 0, 0, 0, 0, 0, 0};
    if (quad < 2) Ae1 = *(const bf8*)(ep + 32 + quad * 8);
    if (quad == 1) {
      Ae1[1] = (short)0x3F80;  // bf16 1.0 at k=41
#pragma unroll
      for (int i = 2; i < 8; ++i) Ae1[i] = 0;
    }

    const f32x4 z = {0.f, 0.f, 0.f, 0.f};
#pragma unroll 1
    for (int ct = 0; ct < 8; ++ct) {
      const bf8 Be0 = *(const bf8*)(Wi + ((ct * 2 + 0) * 64 + lane) * 8);
      const bf8 Be1 = *(const bf8*)(Wi + ((ct * 2 + 1) * 64 + lane) * 8);
      const bf8 Bs0 = *(const bf8*)(Wi + 8192 + ((ct * 2 + 0) * 64 + lane) * 8);
      const bf8 Bs1 = *(const bf8*)(Wi + 8192 + ((ct * 2 + 1) * 64 + lane) * 8);
      const bf8 Bn0 = *(const bf8*)(Wi + 16384 + ((ct * 2 + 0) * 64 + lane) * 8);
      const bf8 Bn1 = *(const bf8*)(Wi + 16384 + ((ct * 2 + 1) * 64 + lane) * 8);
      f32x4 acc = MFMA_B16(Ax0, Bn0, z);
      acc = MFMA_B16(Ax1, Bn1, acc);
      acc = MFMA_B16(As0, Bs0, acc);
      acc = MFMA_B16(As1, Bs1, acc);
      acc = MFMA_B16(Ae0, Be0, acc);
      acc = MFMA_B16(Ae1, Be1, acc);
      // pair flt/core across lane^1; even lanes rows {q4+0,q4+1}, odd {2,3}
      float t0 = __shfl_xor(acc[0], 1);
      float t1 = __shfl_xor(acc[1], 1);
      float t2 = __shfl_xor(acc[2], 1);
      float t3 = __shfl_xor(acc[3], 1);
      const bool odd = (l15 & 1);
      const float f0 = odd ? t2 : acc[0];
      const float c0 = odd ? acc[2] : t0;
      const float f1 = odd ? t3 : acc[1];
      const float c1 = odd ? acc[3] : t1;
      float p = sig(f0) * sp(c0) + sig(f1) * sp(c1);
      if (quad == 3) p = 0.f;  // padded rows 12..15
      p += __shfl_xor(p, 1);   // rows quad*4+0..3
      p += __shfl_xor(p, 16);  // + quad^1
      p += __shfl_xor(p, 32);  // + quad^2 -> full m-sum, all lanes
      if ((ct >> 1) == quad) { // this quad finalizes cols ct*8..ct*8+7
        const int c = ct * 8 + (l15 >> 1);
        const float res = sp(X[(size_t)n * 64 + c] + p * (g2[c] * inv) + b2[c]);
        const unsigned int u = (unsigned short)f2bf(res);
        const unsigned int pu = __shfl_xor((int)u, 2);
        if (!(l15 & 1)) X[(size_t)n * 64 + c] = res;
        if (!(l15 & 3)) XbOutU[(size_t)n * 32 + (c >> 1)] = u | (pu << 16);
      }
    }
  }
}

// ---------------------------------------------------------------------------
// Pool + extra embedding + FC + 3 heads (unchanged).
// ---------------------------------------------------------------------------
__device__ __forceinline__ int lbound(const int* __restrict__ a, int n, int v) {
  int lo = 0, hi = n;
  while (lo < hi) {
    int mid = (lo + hi) >> 1;
    if (a[mid] < v) lo = mid + 1; else hi = mid;
  }
  return lo;
}

__global__ __launch_bounds__(128) void k_head(
    const float* __restrict__ Xf, const int* __restrict__ seg,
    const float* __restrict__ EF, const float* __restrict__ Wx,
    const float* __restrict__ bx, const float* __restrict__ gx,
    const float* __restrict__ bxb, const float* __restrict__ Wfc,
    const float* __restrict__ bfc, const float* __restrict__ Wo0,
    const float* __restrict__ bo0, const float* __restrict__ Wo1,
    const float* __restrict__ bo1, const float* __restrict__ Wo2,
    const float* __restrict__ bo2, float* __restrict__ out) {
  const int b = blockIdx.x;
  const int t = threadIdx.x;
  __shared__ float vbuf[80];
  __shared__ float part[128];
  __shared__ float4 r4[128];
  const int lo = lbound(seg, N_ATOMS, b);
  const int hi = lbound(seg, N_ATOMS, b + 1);
  const int col = t & 63, half = t >> 6;
  float s = 0.f;
  for (int r = lo + half; r < hi; r += 2) s += Xf[(size_t)r * 64 + col];
  part[t] = s;
  __syncthreads();
  if (t < 64) {
    vbuf[t] = (part[t] + part[t + 64]) / fmaxf((float)(hi - lo), 1.f);
  } else if (t < 80) {
    const int e = t - 64;
    float a = bx[e];
#pragma unroll
    for (int k = 0; k < 8; ++k) a += EF[b * 8 + k] * Wx[k * 16 + e];
    a = a * (gx[e] * rsqrtf(1.f + EPSBN)) + bxb[e];
    vbuf[t] = sp(a);
  }
  __syncthreads();
  float h = bfc[t];
#pragma unroll
  for (int k = 0; k < 80; ++k) h += vbuf[k] * Wfc[k * 128 + t];
  h = sp(h);
  r4[t] = make_float4(h * Wo0[t], h * Wo1[2 * t], h * Wo1[2 * t + 1],
                      h * Wo2[t]);
  __syncthreads();
  for (int st2 = 64; st2 > 0; st2 >>= 1) {
    if (t < st2) {
      float4 a = r4[t], c = r4[t + st2];
      r4[t] = make_float4(a.x + c.x, a.y + c.y, a.z + c.z, a.w + c.w);
    }
    __syncthreads();
  }
  if (t == 0) {
    float4 r = r4[0];
    out[b] = r.x + bo0[0];
    float z0 = r.y + bo1[0], z1 = r.z + bo1[1];
    float mx = fmaxf(z0, z1);
    float lse = mx + __logf(__expf(z0 - mx) + __expf(z1 - mx));
    out[B_CRYS + 2 * b] = z0 - lse;
    out[B_CRYS + 2 * b + 1] = z1 - lse;
    out[3 * B_CRYS + b] = r.w + bo2[0];
  }
}

// ---------------------------------------------------------------------------
extern "C" void kernel_launch(void* const* d_in, const int* in_sizes, int n_in,
                              void* d_out, int out_size, void* d_ws,
                              size_t ws_size, hipStream_t stream) {
  const float* atom_fea = (const float*)d_in[0];
  const float* nbr_fea  = (const float*)d_in[1];
  const int*   nbr_idx  = (const int*)d_in[2];
  const int*   seg      = (const int*)d_in[3];
  const float* extra    = (const float*)d_in[4];
  const float* W_embed  = (const float*)d_in[5];
  const float* b_embed  = (const float*)d_in[6];
  const float* conv_W   = (const float*)d_in[7];
  const float* conv_b   = (const float*)d_in[8];
  const float* bn1_g    = (const float*)d_in[9];
  const float* bn1_b    = (const float*)d_in[10];
  const float* bn2_g    = (const float*)d_in[11];
  const float* bn2_b    = (const float*)d_in[12];
  const float* W_extra  = (const float*)d_in[13];
  const float* b_extra  = (const float*)d_in[14];
  const float* bnx_g    = (const float*)d_in[15];
  const float* bnx_b    = (const float*)d_in[16];
  const float* W_fc     = (const float*)d_in[17];
  const float* b_fc     = (const float*)d_in[18];
  const float* W_out0   = (const float*)d_in[19];
  const float* b_out0   = (const float*)d_in[20];
  const float* W_out1   = (const float*)d_in[21];
  const float* b_out1   = (const float*)d_in[22];
  const float* W_out2   = (const float*)d_in[23];
  const float* b_out2   = (const float*)d_in[24];
  float* out = (float*)d_out;

  // ws: X f32 | XbU0 | XbU1 | Wimg = 15.36 + 7.68 + 7.68 + 0.15 MB
  float* x = (float*)d_ws;
  unsigned int* xbu0 = (unsigned int*)(x + (size_t)N_ATOMS * 64);
  unsigned int* xbu1 = xbu0 + (size_t)N_ATOMS * 32;
  unsigned short* Wimg = (unsigned short*)(xbu1 + (size_t)N_ATOMS * 32);

  hipLaunchKernelGGL(k_wprep, dim3((3 * WIMG_L) / 256), dim3(256), 0, stream,
                     conv_W, conv_b, bn1_g, bn1_b, Wimg);
  hipLaunchKernelGGL(k_embed2, dim3(960), dim3(256), 0, stream, atom_fea,
                     W_embed, b_embed, x, xbu0);
  unsigned int* xin = xbu0;
  unsigned int* xout = xbu1;
  for (int i = 0; i < 3; ++i) {
    hipLaunchKernelGGL(k_fused5, dim3(GRID_F), dim3(256), 0, stream, x,
                       (const unsigned short*)xin, xout, nbr_fea, nbr_idx,
                       Wimg + (size_t)i * WIMG_L, bn2_g + i * 64,
                       bn2_b + i * 64);
    unsigned int* tmp = xin;
    xin = xout;
    xout = tmp;
  }
  hipLaunchKernelGGL(k_head, dim3(B_CRYS), dim3(128), 0, stream, x, seg, extra,
                     W_extra, b_extra, bnx_g, bnx_b, W_fc, b_fc, W_out0, b_out0,
                     W_out1, b_out1, W_out2, b_out2, out);
}